// Round 9
// baseline (516.341 us; speedup 1.0000x reference)
//
#include <hip/hip_runtime.h>
#include <cstdint>
#include <cstddef>

#define N_USERS   100000
#define N_NODES   500000
#define DIM       64
#define N_EDGES   2000000
#define BATCH     4096
#define SCAN_B    1024
#define NBLK      ((N_NODES + SCAN_B - 1) / SCAN_B)   // 489
#define X1C_CAP   280000   // |fB| ~230k measured
#define LA_CAP    100000   // |fA| ~60k measured
#define EDG4_BLK  ((N_EDGES / 4 + 255) / 256)         // 1954 blocks, 4 edges/thread
#define PROP_BLK  2048                                // 8192 waves = 32/CU
#define NBMW      (N_NODES / 32)                      // 15625 bitmap words

// ---- LDS histogram geometry (8-bit counters) ----
#define RANGES    31
#define RANGE_SZ  16384                               // nodes per range
#define RANGE_TOT (RANGES * RANGE_SZ)                 // 507904 >= N_NODES
#define HSLICES   32
#define HIST_BLK  (RANGES * HSLICES)                  // 992
#define ESLICE    (N_EDGES / HSLICES)                 // 62500
#define EINT4     (ESLICE / 4)                        // 15625

// ---- expconv interleave: 1 exp2 block : 16 conv blocks ----
#define EC_TOTAL  (EDG4_BLK * 17)                     // 33218 (conv cap 31264 >= 31250)

typedef unsigned char uchar;
typedef unsigned short ushort;
typedef unsigned int uint;

__device__ __forceinline__ ushort f2bf(float f) {
    uint u = __float_as_uint(f);
    uint r = u + 0x7FFFu + ((u >> 16) & 1u);
    return (ushort)(r >> 16);
}
__device__ __forceinline__ float bflo(uint u) { return __uint_as_float(u << 16); }
__device__ __forceinline__ float bfhi(uint u) { return __uint_as_float(u & 0xFFFF0000u); }

__device__ __forceinline__ int getbit(const uint* __restrict__ bm, int i) {
    return (bm[i >> 5] >> (i & 31)) & 1;
}
__device__ __forceinline__ void setbit_dedup(uint* __restrict__ bm, int i) {
    uint m = 1u << (i & 31);
    uint* p = &bm[i >> 5];
    if (!(*p & m)) atomicOr(p, m);   // dedup read skips most RMWs; stale read = harmless redundant RMW
}

// ---------- mark batch indices into three BITMAPS ---------------------------
// Bitmaps (62.5 KB vs 500 KB bytemaps): 2048 nodes/cache-line -> frontier
// gathers in exp passes + scatter mask become L1/L2-hot (R8: those scattered
// byte-gathers were the dominant request cost).
__global__ void k_mark(const int* __restrict__ u, const int* __restrict__ p,
                       const int* __restrict__ n, uint* __restrict__ f3w,
                       uint* __restrict__ fAw, uint* __restrict__ fBw) {
    int i = blockIdx.x * blockDim.x + threadIdx.x;
    if (i >= 3 * BATCH) return;
    int idx;
    if (i < BATCH)          idx = u[i];
    else if (i < 2 * BATCH) idx = p[i - BATCH];
    else                    idx = n[i - 2 * BATCH];
    uint m = 1u << (idx & 31);
    atomicOr(&f3w[idx >> 5], m);
    atomicOr(&fAw[idx >> 5], m);
    atomicOr(&fBw[idx >> 5], m);
}

// ---------- phase A: LDS-range histogram (8-bit) || f3 -> fA expansion ------
__global__ void k_histexp(const int* __restrict__ src, const int* __restrict__ dst,
                          uchar* __restrict__ degp8, const uint* __restrict__ f3w,
                          uint* __restrict__ fAw) {
    __shared__ uint cnt[RANGE_SZ / 4];            // 4096 words = 16 KB
    if (blockIdx.x < HIST_BLK) {
        int s = blockIdx.x / RANGES;              // slice 0..31
        int r = blockIdx.x - s * RANGES;          // range 0..30
        for (int k = threadIdx.x; k < RANGE_SZ / 4; k += 256) cnt[k] = 0;
        __syncthreads();
        int base = r * RANGE_SZ;
        const int4* d4 = (const int4*)(dst + s * ESLICE);
        for (int t = threadIdx.x; t < EINT4; t += 256) {
            int4 d = d4[t];
            uint l;
            l = (uint)(d.x - base); if (l < RANGE_SZ) atomicAdd(&cnt[l >> 2], 1u << ((l & 3) << 3));
            l = (uint)(d.y - base); if (l < RANGE_SZ) atomicAdd(&cnt[l >> 2], 1u << ((l & 3) << 3));
            l = (uint)(d.z - base); if (l < RANGE_SZ) atomicAdd(&cnt[l >> 2], 1u << ((l & 3) << 3));
            l = (uint)(d.w - base); if (l < RANGE_SZ) atomicAdd(&cnt[l >> 2], 1u << ((l & 3) << 3));
        }
        __syncthreads();
        uint* out = (uint*)(degp8 + (size_t)s * RANGE_TOT) + r * (RANGE_SZ / 4);
        for (int k = threadIdx.x; k < RANGE_SZ / 4; k += 256) out[k] = cnt[k];
    } else {
        int t = (blockIdx.x - HIST_BLK) * blockDim.x + threadIdx.x;
        if (t < N_EDGES / 4) {
            int4 s0 = ((const int4*)src)[t];
            int4 d0 = ((const int4*)dst)[t];
            if (getbit(f3w, d0.x)) setbit_dedup(fAw, s0.x);
            if (getbit(f3w, d0.y)) setbit_dedup(fAw, s0.y);
            if (getbit(f3w, d0.z)) setbit_dedup(fAw, s0.z);
            if (getbit(f3w, d0.w)) setbit_dedup(fAw, s0.w);
        }
    }
}

// ---------- phase B: exp2 (fA -> fB, bitmap) || conv-UNSCALED ---------------
// Groups of 17: slot 0 = exp2 block, slots 1..16 = conv blocks.
__global__ void k_expconv(const int* __restrict__ src, const int* __restrict__ dst,
                          const uint* __restrict__ fAw, uint* __restrict__ fBw,
                          const float* __restrict__ emb, ushort* __restrict__ embs) {
    uint b = blockIdx.x;
    uint g = b / 17u;
    uint r = b - g * 17u;
    if (r == 0u) {                                // exp2 block
        int t = (int)g * 256 + threadIdx.x;
        if (t < N_EDGES / 4) {
            int4 s0 = ((const int4*)src)[t];
            int4 d0 = ((const int4*)dst)[t];
            if (getbit(fAw, d0.x)) setbit_dedup(fBw, s0.x);
            if (getbit(fAw, d0.y)) setbit_dedup(fBw, s0.y);
            if (getbit(fAw, d0.z)) setbit_dedup(fBw, s0.z);
            if (getbit(fAw, d0.w)) setbit_dedup(fBw, s0.w);
        }
    } else {                                      // conv block (UNSCALED bf16)
        int c = (int)(g * 16u + r - 1u) * 256 + threadIdx.x;   // 4-float chunk
        if (c < N_NODES * 16) {
            float4 v = ((const float4*)emb)[c];
            uint2 o;
            o.x = (uint)f2bf(v.x) | ((uint)f2bf(v.y) << 16);
            o.y = (uint)f2bf(v.z) | ((uint)f2bf(v.w) << 16);
            ((uint2*)embs)[c] = o;
        }
    }
}

// ---------- scan A: degp8 reduce -> degsum; block sums of deg + flags -------
__global__ void k_scanA(const uchar* __restrict__ degp8, const uint* __restrict__ fAw,
                        const uint* __restrict__ fBw, int* __restrict__ degsum,
                        int* __restrict__ bsumD, int* __restrict__ bsumP) {
    __shared__ int sD[SCAN_B];
    __shared__ int sP[SCAN_B];
    int i = blockIdx.x * SCAN_B + threadIdx.x;
    int d = 0, pk = 0;
    if (i < N_NODES) {
        #pragma unroll
        for (int s = 0; s < HSLICES; ++s) d += (int)degp8[(size_t)s * RANGE_TOT + i];
        degsum[i] = d;
        pk = getbit(fAw, i) | (getbit(fBw, i) << 16);
    }
    sD[threadIdx.x] = d; sP[threadIdx.x] = pk;
    __syncthreads();
    for (int off = SCAN_B / 2; off; off >>= 1) {
        if (threadIdx.x < off) {
            sD[threadIdx.x] += sD[threadIdx.x + off];
            sP[threadIdx.x] += sP[threadIdx.x + off];
        }
        __syncthreads();
    }
    if (threadIdx.x == 0) { bsumD[blockIdx.x] = sD[0]; bsumP[blockIdx.x] = sP[0]; }
}

// ---------- scan B: exclusive scans of block sums ---------------------------
__global__ void k_scanB(const int* __restrict__ bsumD, const int* __restrict__ bsumP,
                        int* __restrict__ boffD, int* __restrict__ boffA,
                        int* __restrict__ boffB, int* __restrict__ counts) {
    __shared__ int sD[512];
    __shared__ int sA[512];
    __shared__ int sB[512];
    int d = (threadIdx.x < NBLK) ? bsumD[threadIdx.x] : 0;
    int p = (threadIdx.x < NBLK) ? bsumP[threadIdx.x] : 0;
    int a = p & 0xFFFF, b = p >> 16;
    sD[threadIdx.x] = d; sA[threadIdx.x] = a; sB[threadIdx.x] = b;
    __syncthreads();
    for (int off = 1; off < 512; off <<= 1) {
        int tD = (threadIdx.x >= off) ? sD[threadIdx.x - off] : 0;
        int tA = (threadIdx.x >= off) ? sA[threadIdx.x - off] : 0;
        int tB = (threadIdx.x >= off) ? sB[threadIdx.x - off] : 0;
        __syncthreads();
        sD[threadIdx.x] += tD; sA[threadIdx.x] += tA; sB[threadIdx.x] += tB;
        __syncthreads();
    }
    if (threadIdx.x < NBLK) {
        boffD[threadIdx.x] = sD[threadIdx.x] - d;
        boffA[threadIdx.x] = sA[threadIdx.x] - a;
        boffB[threadIdx.x] = sB[threadIdx.x] - b;
    }
    if (threadIdx.x == 511) { counts[0] = sA[511]; counts[1] = sB[511]; }
}

// ---------- scan C: rowstart/dinv + mapA/mapB + packed worklists ------------
__global__ void k_scanC(const int* __restrict__ degsum, const uint* __restrict__ fAw,
                        const uint* __restrict__ fBw,
                        const int* __restrict__ boffD, const int* __restrict__ boffA,
                        const int* __restrict__ boffB,
                        int* __restrict__ rowstart, float* __restrict__ dinv,
                        int* __restrict__ mapA, int* __restrict__ mapB,
                        int4* __restrict__ listA4, int4* __restrict__ listB4) {
    __shared__ int sD[SCAN_B];
    __shared__ int sP[SCAN_B];
    int i = blockIdx.x * SCAN_B + threadIdx.x;
    int d = 0, a = 0, b = 0;
    if (i < N_NODES) {
        d = degsum[i];
        a = getbit(fAw, i);
        b = getbit(fBw, i);
    }
    sD[threadIdx.x] = d; sP[threadIdx.x] = a | (b << 16);
    __syncthreads();
    for (int off = 1; off < SCAN_B; off <<= 1) {
        int tD = (threadIdx.x >= off) ? sD[threadIdx.x - off] : 0;
        int tP = (threadIdx.x >= off) ? sP[threadIdx.x - off] : 0;
        __syncthreads();
        sD[threadIdx.x] += tD; sP[threadIdx.x] += tP;
        __syncthreads();
    }
    if (i < N_NODES) {
        int exD = sD[threadIdx.x] - d + boffD[blockIdx.x];
        int incP = sP[threadIdx.x];
        int exA = (incP & 0xFFFF) - a + boffA[blockIdx.x];
        int exB = (incP >> 16) - b + boffB[blockIdx.x];
        rowstart[i] = exD;
        float dv = (d > 0) ? rsqrtf((float)d) : 0.0f;
        dinv[i] = dv;
        mapA[i] = a ? exA : -1;
        mapB[i] = b ? exB : -1;
        int4 ent = make_int4(exD, exD + d, __float_as_int(dv), 0);
        if (a) listA4[exA] = ent;
        if (b) listB4[exB] = ent;
    }
}

// ---------- masked scatter ALONE (920k fabric RMW ~= 40us floor) ------------
__global__ void k_scatter(const int* __restrict__ src, const int* __restrict__ dst,
                          const uint* __restrict__ fBw, int* __restrict__ rowstart,
                          int* __restrict__ csr_src) {
    int t = blockIdx.x * blockDim.x + threadIdx.x;
    if (t < N_EDGES / 4) {
        int4 s0 = ((const int4*)src)[t];
        int4 d0 = ((const int4*)dst)[t];
        if (getbit(fBw, d0.x)) csr_src[atomicAdd(&rowstart[d0.x], 1)] = s0.x;
        if (getbit(fBw, d0.y)) csr_src[atomicAdd(&rowstart[d0.y], 1)] = s0.y;
        if (getbit(fBw, d0.z)) csr_src[atomicAdd(&rowstart[d0.z], 1)] = s0.z;
        if (getbit(fBw, d0.w)) csr_src[atomicAdd(&rowstart[d0.w], 1)] = s0.w;
    }
}

// ---------- layer 1: embs(bf16 UNSCALED) -> x1c(bf16, x1*dinv[node]) --------
// 8-sub x 8-lane uint4 tiling: 8 requests/edge of 16 B (was 16 of 8 B) —
// halves the gather request count for the same bytes.
__global__ void k_prop1(const ushort* __restrict__ embs, const int4* __restrict__ listB4,
                        const int* __restrict__ counts, const int* __restrict__ csr_src,
                        const float* __restrict__ dinv, ushort* __restrict__ x1c) {
    int lane = threadIdx.x & 63;
    int sub = lane >> 3, q = lane & 7;
    int wv = (blockIdx.x * blockDim.x + threadIdx.x) >> 6;
    int nw = (gridDim.x * blockDim.x) >> 6;
    int cnt = counts[1];
    for (; wv < cnt; wv += nw) {
        int4 nb = listB4[wv];
        float a0 = 0.f, a1 = 0.f, a2 = 0.f, a3 = 0.f;
        float a4 = 0.f, a5 = 0.f, a6 = 0.f, a7 = 0.f;
        for (int i = nb.x + sub; i < nb.y; i += 8) {
            int s = csr_src[i];
            float dvs = dinv[s];
            uint4 u = *(const uint4*)(embs + (size_t)s * DIM + q * 8);
            a0 = fmaf(bflo(u.x), dvs, a0); a1 = fmaf(bfhi(u.x), dvs, a1);
            a2 = fmaf(bflo(u.y), dvs, a2); a3 = fmaf(bfhi(u.y), dvs, a3);
            a4 = fmaf(bflo(u.z), dvs, a4); a5 = fmaf(bfhi(u.z), dvs, a5);
            a6 = fmaf(bflo(u.w), dvs, a6); a7 = fmaf(bfhi(u.w), dvs, a7);
        }
        for (int off = 8; off <= 32; off <<= 1) {
            a0 += __shfl_xor(a0, off, 64); a1 += __shfl_xor(a1, off, 64);
            a2 += __shfl_xor(a2, off, 64); a3 += __shfl_xor(a3, off, 64);
            a4 += __shfl_xor(a4, off, 64); a5 += __shfl_xor(a5, off, 64);
            a6 += __shfl_xor(a6, off, 64); a7 += __shfl_xor(a7, off, 64);
        }
        if (sub == 0) {
            float dv = __int_as_float(nb.z);
            float d2 = dv * dv;   // store x1*dinv[node] for next layer
            uint4 o;
            o.x = (uint)f2bf(a0 * d2) | ((uint)f2bf(a1 * d2) << 16);
            o.y = (uint)f2bf(a2 * d2) | ((uint)f2bf(a3 * d2) << 16);
            o.z = (uint)f2bf(a4 * d2) | ((uint)f2bf(a5 * d2) << 16);
            o.w = (uint)f2bf(a6 * d2) | ((uint)f2bf(a7 * d2) << 16);
            *(uint4*)(x1c + (size_t)wv * DIM + q * 8) = o;
        }
    }
}

// ---------- layer 2: x1c -> x2c (bf16, x2*dinv[node]), same tiling ----------
__global__ void k_prop2(const ushort* __restrict__ x1c, const int* __restrict__ mapB,
                        const int4* __restrict__ listA4, const int* __restrict__ counts,
                        const int* __restrict__ csr_src, ushort* __restrict__ x2c) {
    int lane = threadIdx.x & 63;
    int sub = lane >> 3, q = lane & 7;
    int wv = (blockIdx.x * blockDim.x + threadIdx.x) >> 6;
    int nw = (gridDim.x * blockDim.x) >> 6;
    int cnt = counts[0];
    for (; wv < cnt; wv += nw) {
        int4 nb = listA4[wv];
        float a0 = 0.f, a1 = 0.f, a2 = 0.f, a3 = 0.f;
        float a4 = 0.f, a5 = 0.f, a6 = 0.f, a7 = 0.f;
        for (int i = nb.x + sub; i < nb.y; i += 8) {
            int s = csr_src[i];
            int slot = mapB[s];
            uint4 u = *(const uint4*)(x1c + (size_t)slot * DIM + q * 8);
            a0 += bflo(u.x); a1 += bfhi(u.x);
            a2 += bflo(u.y); a3 += bfhi(u.y);
            a4 += bflo(u.z); a5 += bfhi(u.z);
            a6 += bflo(u.w); a7 += bfhi(u.w);
        }
        for (int off = 8; off <= 32; off <<= 1) {
            a0 += __shfl_xor(a0, off, 64); a1 += __shfl_xor(a1, off, 64);
            a2 += __shfl_xor(a2, off, 64); a3 += __shfl_xor(a3, off, 64);
            a4 += __shfl_xor(a4, off, 64); a5 += __shfl_xor(a5, off, 64);
            a6 += __shfl_xor(a6, off, 64); a7 += __shfl_xor(a7, off, 64);
        }
        if (sub == 0) {
            float dv = __int_as_float(nb.z);
            float d2 = dv * dv;
            uint4 o;
            o.x = (uint)f2bf(a0 * d2) | ((uint)f2bf(a1 * d2) << 16);
            o.y = (uint)f2bf(a2 * d2) | ((uint)f2bf(a3 * d2) << 16);
            o.z = (uint)f2bf(a4 * d2) | ((uint)f2bf(a5 * d2) << 16);
            o.w = (uint)f2bf(a6 * d2) | ((uint)f2bf(a7 * d2) << 16);
            *(uint4*)(x2c + (size_t)wv * DIM + q * 8) = o;
        }
    }
}

// ---------- fused layer 3 + loss: wave per batch item -----------------------
__device__ __forceinline__ float x3_row(const ushort* __restrict__ x2c,
                                        const int* __restrict__ mapA,
                                        const int* __restrict__ csr_src,
                                        const int4* __restrict__ listB4,
                                        const int* __restrict__ mapB,
                                        int t, int lane) {
    int4 nb = listB4[mapB[t]];
    float acc = 0.f;
    for (int i = nb.x; i < nb.y; ++i) {
        int s = csr_src[i];
        int slot = mapA[s];
        acc += __uint_as_float((uint)x2c[(size_t)slot * DIM + lane] << 16);
    }
    return acc * __int_as_float(nb.z);
}

__global__ void k_loss(const float* __restrict__ emb, const ushort* __restrict__ x1c,
                       const ushort* __restrict__ x2c,
                       const int* __restrict__ mapA, const int* __restrict__ mapB,
                       const int4* __restrict__ listB4, const int* __restrict__ csr_src,
                       const float* __restrict__ dinv,
                       const int* __restrict__ u, const int* __restrict__ p,
                       const int* __restrict__ n, float* __restrict__ out) {
    int lane = threadIdx.x & 63;
    int w = (blockIdx.x * blockDim.x + threadIdx.x) >> 6;
    if (w >= BATCH) return;
    int ui = u[w], pi = p[w], ni = n[w];
    float dvu = dinv[ui], dvp = dinv[pi], dvn = dinv[ni];
    float rdu = dvu > 0.f ? 1.f / dvu : 0.f;
    float rdp = dvp > 0.f ? 1.f / dvp : 0.f;
    float rdn = dvn > 0.f ? 1.f / dvn : 0.f;
    float ue = emb[(size_t)ui * DIM + lane];
    float pe = emb[(size_t)pi * DIM + lane];
    float ne = emb[(size_t)ni * DIM + lane];
    float u1 = __uint_as_float((uint)x1c[(size_t)mapB[ui] * DIM + lane] << 16) * rdu;
    float p1 = __uint_as_float((uint)x1c[(size_t)mapB[pi] * DIM + lane] << 16) * rdp;
    float n1 = __uint_as_float((uint)x1c[(size_t)mapB[ni] * DIM + lane] << 16) * rdn;
    float u2 = __uint_as_float((uint)x2c[(size_t)mapA[ui] * DIM + lane] << 16) * rdu;
    float p2 = __uint_as_float((uint)x2c[(size_t)mapA[pi] * DIM + lane] << 16) * rdp;
    float n2 = __uint_as_float((uint)x2c[(size_t)mapA[ni] * DIM + lane] << 16) * rdn;
    float u3 = x3_row(x2c, mapA, csr_src, listB4, mapB, ui, lane);
    float p3 = x3_row(x2c, mapA, csr_src, listB4, mapB, pi, lane);
    float n3 = x3_row(x2c, mapA, csr_src, listB4, mapB, ni, lane);
    float uall = 0.25f * (ue + u1 + u2 + u3);
    float pall = 0.25f * (pe + p1 + p2 + p3);
    float nall = 0.25f * (ne + n1 + n2 + n3);
    float pos = uall * pall;
    float neg = uall * nall;
    float sq  = ue * ue + pe * pe + ne * ne;
    for (int off = 32; off; off >>= 1) {
        pos += __shfl_xor(pos, off, 64);
        neg += __shfl_xor(neg, off, 64);
        sq  += __shfl_xor(sq,  off, 64);
    }
    if (lane == 0) {
        float z = neg - pos;
        float sp = fmaxf(z, 0.0f) + log1pf(expf(-fabsf(z)));
        float contrib = sp * (1.0f / BATCH) + 1e-4f * 0.5f * sq * (1.0f / BATCH);
        atomicAdd(out, contrib);
    }
}

extern "C" void kernel_launch(void* const* d_in, const int* in_sizes, int n_in,
                              void* d_out, int out_size, void* d_ws, size_t ws_size,
                              hipStream_t stream) {
    const float* emb  = (const float*)d_in[0];
    const int*   edge = (const int*)d_in[1];
    const int*   src  = edge;
    const int*   dst  = edge + N_EDGES;
    const int*   uidx = (const int*)d_in[2];
    const int*   pidx = (const int*)d_in[3];
    const int*   nidx = (const int*)d_in[4];
    float* out = (float*)d_out;

    // ---- workspace layout (~160 MB) ----
    char* w = (char*)d_ws;
    ushort* embs    = (ushort*)w;                w += (size_t)N_NODES * DIM * 2;   // 64 MB
    ushort* x1c     = (ushort*)w;                w += (size_t)X1C_CAP * DIM * 2;   // 35.8 MB
    ushort* x2c     = (ushort*)w;                w += (size_t)LA_CAP * DIM * 2;    // 12.8 MB
    float*  dinv    = (float*)w;                 w += (size_t)N_NODES * 4;
    int*    rowstart= (int*)w;                   w += (size_t)N_NODES * 4;
    int*    csr_src = (int*)w;                   w += (size_t)N_EDGES * 4;
    int*    mapA    = (int*)w;                   w += (size_t)N_NODES * 4;
    int*    mapB    = (int*)w;                   w += (size_t)N_NODES * 4;
    int*    degsum  = (int*)w;                   w += (size_t)N_NODES * 4;
    int4*   listA4  = (int4*)w;                  w += (size_t)LA_CAP * 16;
    int4*   listB4  = (int4*)w;                  w += (size_t)X1C_CAP * 16;
    uchar*  degp8   = (uchar*)w;                 w += (size_t)HSLICES * RANGE_TOT; // 15.5 MB, NOT zeroed (fully overwritten)
    // --- zeroed region (single memset): three bitmaps, 187.5 KB total ---
    char*   zbase   = w;
    uint*   f3w     = (uint*)w;                  w += (size_t)NBMW * 4;
    uint*   fAw     = (uint*)w;                  w += (size_t)NBMW * 4;
    uint*   fBw     = (uint*)w;                  w += (size_t)NBMW * 4;
    size_t  zbytes  = (size_t)(w - zbase);
    int*    bsumD   = (int*)w;                   w += (size_t)NBLK * 4;
    int*    boffD   = (int*)w;                   w += (size_t)NBLK * 4;
    int*    bsumP   = (int*)w;                   w += (size_t)NBLK * 4;
    int*    boffA   = (int*)w;                   w += (size_t)NBLK * 4;
    int*    boffB   = (int*)w;                   w += (size_t)NBLK * 4;
    int*    counts  = (int*)w;                   w += 16;   // [0]=|fA|, [1]=|fB|

    hipMemsetAsync(zbase, 0, zbytes, stream);
    hipMemsetAsync(out, 0, 4, stream);

    // batch marks (bitmaps)
    k_mark<<<(3 * BATCH + 255) / 256, 256, 0, stream>>>(uidx, pidx, nidx, f3w, fAw, fBw);

    // phase A: histogram (dst only) || exp1 (f3 -> fA, bitmap-hot)
    k_histexp<<<HIST_BLK + EDG4_BLK, 256, 0, stream>>>(src, dst, degp8, f3w, fAw);

    // phase B: exp2 (fA -> fB, bitmap-hot) || conv-unscaled
    k_expconv<<<EC_TOTAL, 256, 0, stream>>>(src, dst, fAw, fBw, emb, embs);

    // scan trio: degp8 reduce + CSR offsets + dinv + maps + worklists
    k_scanA<<<NBLK, SCAN_B, 0, stream>>>(degp8, fAw, fBw, degsum, bsumD, bsumP);
    k_scanB<<<1, 512, 0, stream>>>(bsumD, bsumP, boffD, boffA, boffB, counts);
    k_scanC<<<NBLK, SCAN_B, 0, stream>>>(degsum, fAw, fBw, boffD, boffA, boffB,
                                         rowstart, dinv, mapA, mapB, listA4, listB4);

    // masked atomic CSR fill, ALONE (fabric atomics throttle any co-resident)
    k_scatter<<<EDG4_BLK, 256, 0, stream>>>(src, dst, fBw, rowstart, csr_src);

    // sparse propagation (persistent grid-stride, request-halved uint4 tiling)
    k_prop1<<<PROP_BLK, 256, 0, stream>>>(embs, listB4, counts, csr_src, dinv, x1c);
    k_prop2<<<PROP_BLK, 256, 0, stream>>>(x1c, mapB, listA4, counts, csr_src, x2c);

    // fused layer-3 + loss
    k_loss<<<(BATCH * 64 + 255) / 256, 256, 0, stream>>>(
        emb, x1c, x2c, mapA, mapB, listB4, csr_src, dinv, uidx, pidx, nidx, out);
}